// Round 1
// baseline (3280.338 us; speedup 1.0000x reference)
//
#include <hip/hip_runtime.h>
#include <cstdint>

#define TT 128
#define BB 128
#define HH 512

typedef _Float16 f16;
typedef _Float16 f16x8 __attribute__((ext_vector_type(8)));
typedef float f32x4 __attribute__((ext_vector_type(4)));
typedef unsigned int u32;

// ---- workspace layout (bytes) ----
#define OFF_H0    4096                  // enc layer0 h, [2][128][512] f16 (swizzled rows)
#define OFF_H1    (OFF_H0 + 262144)     // enc layer1 h
#define OFF_D0    (OFF_H1 + 262144)     // dec layer0 h
#define OFF_D1    (OFF_D0 + 262144)     // dec layer1 h
#define OFF_XH    (OFF_D1 + 262144)     // x as f16, [T][128][64], row-swizzled
#define OFF_HS    (OFF_XH + 2097152)    // decoder outputs [T][128][512] f16 (plain)

// ---- LDS layout (bytes) ----
#define L_WA   0          // [32][576] f16: cols 0-63 = W_ih0 (x part), 64-575 = W_hh0
#define L_WB   36864      // [32][512] f16: W_ih1
#define L_WC   69632      // [32][512] f16: W_hh1
#define L_HA   102400     // 2 x [32][128] f16 chunk double-buffer (layer-0 h / enc1 input)
#define L_HB   118784     // 2 x [32][128] f16 chunk double-buffer (layer-1 h)
#define L_X    135168     // [32][64] f16 staged x tile
#define L_P0   139264     // [32][33] f32 gate preacts layer0
#define L_P1   143488     // [32][33] f32 gate preacts layer1
#define L_B0   147712     // 32 f32 bias layer0
#define L_B1   147840     // 32 f32 bias layer1
#define L_TOT  147968

#define MFMA16(a,b,c) __builtin_amdgcn_mfma_f32_16x16x32_f16((a),(b),(c),0,0,0)

__device__ __forceinline__ float sigm(float x){ return 1.f/(1.f+__expf(-x)); }
__device__ __forceinline__ float tanhft(float x){ return 1.f - 2.f/(__expf(2.f*x)+1.f); }

// fragment read from a row-major LDS tile whose rows are XOR-swizzled in 16B blocks
__device__ __forceinline__ f16x8 lfrag(const char* base, int stride, int row, int kbyte){
  return *(const f16x8*)(base + row*stride + (kbyte ^ ((row & 7) << 4)));
}

// stage one 128-k chunk (32 rows x 256B) of an H buffer slice into LDS (linear copy;
// the global buffer is already stored row-swizzled, so swizzle is preserved)
__device__ __forceinline__ void stageH(char* dst, const char* src, int c, int tid){
#pragma unroll
  for (int it = 0; it < 2; ++it){
    int q = tid + (it << 8);
    *(f16x8*)(dst + (q<<4)) =
      *(const f16x8*)(src + ((q>>4)<<10) + (c<<8) + ((q&15)<<4));
  }
}

// load a 32-gate-row weight slice (fp32 global -> fp16 LDS, row-swizzled).
// slice rows r=0..31: gate = r>>3 (i,f,g,o), h-col = cg*8 + (r&7)
__device__ __forceinline__ void load_w(char* dst, int rs, const float* __restrict__ src,
                                       int Ksrc, int dstoff, int cg, int tid){
  const int upr = Ksrc >> 2;
  for (int q = tid; q < (upr << 5); q += 256){
    int r = q / upr, kq = q - r*upr;
    int srow = ((r>>3)<<9) + (cg<<3) + (r&7);
    float4 v = *(const float4*)(src + srow*Ksrc + (kq<<2));
    int by = (dstoff + (kq<<3)) ^ ((r&7)<<4);
    f16* p = (f16*)(dst + r*rs + by);
    p[0]=(f16)v.x; p[1]=(f16)v.y; p[2]=(f16)v.z; p[3]=(f16)v.w;
  }
}

// group-local (64 WG) barrier: flag store + all-flag scan + acquire fence.
// __syncthreads() drains vmcnt(0) first, so all agent-scope data stores are at the
// coherence point before the flag publishes.
__device__ __forceinline__ void gbar(int* fl, int cg, int tid, int target){
  __syncthreads();
  if (tid == 0)
    __hip_atomic_store(&fl[cg], target, __ATOMIC_RELAXED, __HIP_MEMORY_SCOPE_AGENT);
  int ok;
  do {
    __builtin_amdgcn_s_sleep(1);
    ok = 1;
    if (tid < 64)
      ok = (__hip_atomic_load(&fl[tid], __ATOMIC_RELAXED, __HIP_MEMORY_SCOPE_AGENT) >= target);
  } while (!__syncthreads_and(ok));
  __builtin_amdgcn_fence(__ATOMIC_ACQUIRE, "agent");  // invalidate stale L1/L2 before reading peers' h
}

// convert x [B][T][64] f32 -> xh [T][128][64] f16, rows XOR-swizzled in 16B blocks
__global__ void cvt_x(const float* __restrict__ x, char* __restrict__ ws){
  int idx = blockIdx.x*256 + threadIdx.x;        // 131072 = T*B*8 units of 16B
  int t = idx >> 10, rem = idx & 1023, b = rem >> 3, blk = rem & 7;
  const float* s = x + (((b<<7) + t)<<6) + (blk<<3);
  float4 v0 = *(const float4*)s, v1 = *(const float4*)(s+4);
  f16x8 h;
  h[0]=(f16)v0.x; h[1]=(f16)v0.y; h[2]=(f16)v0.z; h[3]=(f16)v0.w;
  h[4]=(f16)v1.x; h[5]=(f16)v1.y; h[6]=(f16)v1.z; h[7]=(f16)v1.w;
  int db = blk ^ (b & 7);
  *(f16x8*)(ws + OFF_XH + (((t<<7)+b)<<7) + (db<<4)) = h;
}

__global__ __launch_bounds__(256, 1) void lstm_persist(
    const float* __restrict__ eWih0, const float* __restrict__ eWhh0,
    const float* __restrict__ ebi0,  const float* __restrict__ ebh0,
    const float* __restrict__ eWih1, const float* __restrict__ eWhh1,
    const float* __restrict__ ebi1,  const float* __restrict__ ebh1,
    const float* __restrict__ dWih0, const float* __restrict__ dWhh0,
    const float* __restrict__ dbi0,  const float* __restrict__ dbh0,
    const float* __restrict__ dWih1, const float* __restrict__ dWhh1,
    const float* __restrict__ dbi1,  const float* __restrict__ dbh1,
    const float* __restrict__ fcW,   const float* __restrict__ fcb,
    float* __restrict__ out, char* __restrict__ ws)
{
  __shared__ __align__(16) char lds[L_TOT];
  const int tid  = threadIdx.x;
  const int wg   = blockIdx.x;
  const int g    = wg >> 6;            // batch group (32 rows each) - groups fully independent
  const int cg   = wg & 63;            // column group (8 h-cols = 32 gate-cols)
  const int b0   = g << 5;
  const int lane = tid & 63, wave = tid >> 6;
  const int mi = wave >> 1, ni = wave & 1;       // wave -> 16x16 C tile (2x2)
  const int arow = (mi<<4) + (lane & 15);        // A frag: row = lane&15 (+tile), k-run = (lane>>4)*8
  const int brow = (ni<<4) + (lane & 15);        // B frag: W row (= output col), same k-run
  const int klb  = (lane >> 4) << 4;             // byte offset of lane's 8-elem k-run in a 32k chunk
  const int pcol = (ni<<4) + (lane & 15);
  const int rb = tid >> 3, hcl = tid & 7;        // recombine mapping: thread = (row, h-col)

  int* flags = (int*)ws + (g<<6);
  char* H0 = ws + OFF_H0;  char* H1 = ws + OFF_H1;
  char* D0 = ws + OFF_D0;  char* D1 = ws + OFF_D1;
  const char* XH = ws + OFF_XH;
  char* HS = ws + OFF_HS;

  char* WAp = lds + L_WA; char* WBp = lds + L_WB; char* WCp = lds + L_WC;
  char* HAp = lds + L_HA; char* HBp = lds + L_HB; char* Xp = lds + L_X;
  float* P0 = (float*)(lds + L_P0); float* P1 = (float*)(lds + L_P1);
  float* B0 = (float*)(lds + L_B0); float* B1 = (float*)(lds + L_B1);

  // ---- encoder weights -> LDS ----
  load_w(WAp, 1152, eWih0,  64,   0, cg, tid);
  load_w(WAp, 1152, eWhh0, 512, 128, cg, tid);
  load_w(WBp, 1024, eWih1, 512,   0, cg, tid);
  load_w(WCp, 1024, eWhh1, 512,   0, cg, tid);
  if (tid < 32){
    int srow = ((tid>>3)<<9) + (cg<<3) + (tid&7);
    B0[tid] = ebi0[srow] + ebh0[srow];
    B1[tid] = ebi1[srow] + ebh1[srow];
  }
  __syncthreads();

  float c0v = 0.f, c1v = 0.f;
  int bt = 0;

  // ================= encoder: layers 0+1 pipelined, 1 barrier/step =================
  for (int s = 0; s <= TT; ++s){
    const bool d0 = (s < TT), d1 = (s >= 1);
    const char* R0 = H0 + ((s&1)<<17) + (b0<<10);
    const char* R1 = H1 + ((s&1)<<17) + (b0<<10);
    char* W0 = H0 + (((s+1)&1)<<17) + (b0<<10);
    char* W1 = H1 + (((s+1)&1)<<17) + (b0<<10);

    f32x4 acc0 = {0.f,0.f,0.f,0.f}, acc1 = {0.f,0.f,0.f,0.f};

    if (d0)
      *(f16x8*)(Xp + (tid<<4)) = *(const f16x8*)(XH + (((s<<7)+b0)<<7) + (tid<<4));
    stageH(HAp, R0, 0, tid);
    stageH(HBp, R1, 0, tid);
    __syncthreads();

    if (d0){                                    // x @ W_ih0 (K=64)
#pragma unroll
      for (int sub = 0; sub < 2; ++sub){
        int kb = (sub<<6) + klb;
        acc0 = MFMA16(lfrag(Xp,128,arow,kb), lfrag(WAp,1152,brow,kb), acc0);
      }
    }
    for (int c = 0; c < 4; ++c){                // K=512 in 4 chunks, double-buffered
      const char* cA = (c&1) ? (HAp+8192) : HAp;
      const char* cB = (c&1) ? (HBp+8192) : HBp;
      if (c < 3){
        stageH((c&1)?HAp:(HAp+8192), R0, c+1, tid);
        stageH((c&1)?HBp:(HBp+8192), R1, c+1, tid);
      }
#pragma unroll
      for (int sub = 0; sub < 4; ++sub){
        int kb = (sub<<6) + klb;
        f16x8 a0 = lfrag(cA, 256, arow, kb);                       // h0[t-1] serves BOTH layers
        acc0 = MFMA16(a0, lfrag(WAp,1152,brow, 128+(c<<8)+kb), acc0);
        acc1 = MFMA16(a0, lfrag(WBp,1024,brow, (c<<8)+kb), acc1);
        f16x8 a1 = lfrag(cB, 256, arow, kb);
        acc1 = MFMA16(a1, lfrag(WCp,1024,brow, (c<<8)+kb), acc1);
      }
      __syncthreads();
    }

#pragma unroll
    for (int r = 0; r < 4; ++r){               // C layout: col=lane&15, row=(lane>>4)*4+r (m89)
      int prow = (mi<<4) + ((lane>>4)<<2) + r;
      P0[prow*33 + pcol] = acc0[r];
      P1[prow*33 + pcol] = acc1[r];
    }
    __syncthreads();

    if (d0){
      float gi = sigm  (P0[rb*33 +      hcl] + B0[hcl]);
      float gf = sigm  (P0[rb*33 +  8 + hcl] + B0[8+hcl]);
      float gg = tanhft(P0[rb*33 + 16 + hcl] + B0[16+hcl]);
      float go = sigm  (P0[rb*33 + 24 + hcl] + B0[24+hcl]);
      c0v = gf*c0v + gi*gg;
      float h = go * tanhft(c0v);
      union { f16 hf; unsigned short su; } cv; cv.hf = (f16)h;
      u32 other = (u32)__shfl_xor((int)(u32)cv.su, 1, 64);
      if (!(hcl & 1)){
        u32 pk = (u32)cv.su | (other << 16);
        int blk = cg ^ (rb & 7);
        __hip_atomic_store((u32*)(W0 + (rb<<10) + (blk<<4) + (hcl<<1)), pk,
                           __ATOMIC_RELAXED, __HIP_MEMORY_SCOPE_AGENT);
      }
    }
    if (d1){
      float gi = sigm  (P1[rb*33 +      hcl] + B1[hcl]);
      float gf = sigm  (P1[rb*33 +  8 + hcl] + B1[8+hcl]);
      float gg = tanhft(P1[rb*33 + 16 + hcl] + B1[16+hcl]);
      float go = sigm  (P1[rb*33 + 24 + hcl] + B1[24+hcl]);
      c1v = gf*c1v + gi*gg;
      float h = go * tanhft(c1v);
      union { f16 hf; unsigned short su; } cv; cv.hf = (f16)h;
      u32 other = (u32)__shfl_xor((int)(u32)cv.su, 1, 64);
      if (!(hcl & 1)){
        u32 pk = (u32)cv.su | (other << 16);
        int blk = cg ^ (rb & 7);
        __hip_atomic_store((u32*)(W1 + (rb<<10) + (blk<<4) + (hcl<<1)), pk,
                           __ATOMIC_RELAXED, __HIP_MEMORY_SCOPE_AGENT);
      }
    }
    gbar(flags, cg, tid, ++bt);
  }

  // ================= zx = z @ dW_ih0 + biases (one-time, kept in regs) =================
  load_w(WAp, 1152, dWih0, 512, 128, cg, tid);
  __syncthreads();
  f32x4 zx;
  {
    int srow = ((pcol>>3)<<9) + (cg<<3) + (pcol&7);
    float zb = dbi0[srow] + dbh0[srow];
    zx[0]=zb; zx[1]=zb; zx[2]=zb; zx[3]=zb;
  }
  {
    const char* ZR = H1 + (1<<17) + (b0<<10);   // z = final enc1 h, parity (T+1)&1 = 1
    for (int c = 0; c < 4; ++c){
      stageH(HAp, ZR, c, tid);
      __syncthreads();
#pragma unroll
      for (int sub = 0; sub < 4; ++sub){
        int kb = (sub<<6) + klb;
        zx = MFMA16(lfrag(HAp,256,arow,kb), lfrag(WAp,1152,brow, 128+(c<<8)+kb), zx);
      }
      __syncthreads();
    }
  }

  // ---- decoder weights -> LDS ----
  load_w(WAp, 1152, dWhh0, 512, 128, cg, tid);
  load_w(WBp, 1024, dWih1, 512,   0, cg, tid);
  load_w(WCp, 1024, dWhh1, 512,   0, cg, tid);
  if (tid < 32){
    int srow = ((tid>>3)<<9) + (cg<<3) + (tid&7);
    B1[tid] = dbi1[srow] + dbh1[srow];
  }
  __syncthreads();
  c0v = 0.f; c1v = 0.f;

  // ================= decoder: layers 0+1 pipelined =================
  for (int s = 0; s <= TT; ++s){
    const bool d0 = (s < TT), d1 = (s >= 1);
    const char* R0 = D0 + ((s&1)<<17) + (b0<<10);
    const char* R1 = D1 + ((s&1)<<17) + (b0<<10);
    char* W0 = D0 + (((s+1)&1)<<17) + (b0<<10);
    char* W1 = D1 + (((s+1)&1)<<17) + (b0<<10);

    f32x4 acc0 = zx, acc1 = {0.f,0.f,0.f,0.f};  // constant-z input product preloaded

    stageH(HAp, R0, 0, tid);
    stageH(HBp, R1, 0, tid);
    __syncthreads();

    for (int c = 0; c < 4; ++c){
      const char* cA = (c&1) ? (HAp+8192) : HAp;
      const char* cB = (c&1) ? (HBp+8192) : HBp;
      if (c < 3){
        stageH((c&1)?HAp:(HAp+8192), R0, c+1, tid);
        stageH((c&1)?HBp:(HBp+8192), R1, c+1, tid);
      }
#pragma unroll
      for (int sub = 0; sub < 4; ++sub){
        int kb = (sub<<6) + klb;
        f16x8 a0 = lfrag(cA, 256, arow, kb);
        acc0 = MFMA16(a0, lfrag(WAp,1152,brow, 128+(c<<8)+kb), acc0);
        acc1 = MFMA16(a0, lfrag(WBp,1024,brow, (c<<8)+kb), acc1);
        f16x8 a1 = lfrag(cB, 256, arow, kb);
        acc1 = MFMA16(a1, lfrag(WCp,1024,brow, (c<<8)+kb), acc1);
      }
      __syncthreads();
    }

#pragma unroll
    for (int r = 0; r < 4; ++r){
      int prow = (mi<<4) + ((lane>>4)<<2) + r;
      P0[prow*33 + pcol] = acc0[r];
      P1[prow*33 + pcol] = acc1[r];
    }
    __syncthreads();

    if (d0){
      float gi = sigm  (P0[rb*33 +      hcl]);   // biases already inside zx
      float gf = sigm  (P0[rb*33 +  8 + hcl]);
      float gg = tanhft(P0[rb*33 + 16 + hcl]);
      float go = sigm  (P0[rb*33 + 24 + hcl]);
      c0v = gf*c0v + gi*gg;
      float h = go * tanhft(c0v);
      union { f16 hf; unsigned short su; } cv; cv.hf = (f16)h;
      u32 other = (u32)__shfl_xor((int)(u32)cv.su, 1, 64);
      if (!(hcl & 1)){
        u32 pk = (u32)cv.su | (other << 16);
        int blk = cg ^ (rb & 7);
        __hip_atomic_store((u32*)(W0 + (rb<<10) + (blk<<4) + (hcl<<1)), pk,
                           __ATOMIC_RELAXED, __HIP_MEMORY_SCOPE_AGENT);
      }
    }
    if (d1){
      float gi = sigm  (P1[rb*33 +      hcl] + B1[hcl]);
      float gf = sigm  (P1[rb*33 +  8 + hcl] + B1[8+hcl]);
      float gg = tanhft(P1[rb*33 + 16 + hcl] + B1[16+hcl]);
      float go = sigm  (P1[rb*33 + 24 + hcl] + B1[24+hcl]);
      c1v = gf*c1v + gi*gg;
      float h = go * tanhft(c1v);
      union { f16 hf; unsigned short su; } cv; cv.hf = (f16)h;
      u32 other = (u32)__shfl_xor((int)(u32)cv.su, 1, 64);
      if (!(hcl & 1)){
        u32 pk = (u32)cv.su | (other << 16);
        int blk = cg ^ (rb & 7);
        __hip_atomic_store((u32*)(W1 + (rb<<10) + (blk<<4) + (hcl<<1)), pk,
                           __ATOMIC_RELAXED, __HIP_MEMORY_SCOPE_AGENT);
        // plain-layout copy for fc
        __hip_atomic_store((u32*)(HS + ((((s-1)<<7) + b0 + rb)<<10) + (cg<<4) + (hcl<<1)), pk,
                           __ATOMIC_RELAXED, __HIP_MEMORY_SCOPE_AGENT);
      }
    }
    gbar(flags, cg, tid, ++bt);
  }

  // ================= fc: out[b][t][:] = HS[t][b][:] @ fcW^T + fcb (group-local) =================
  for (int q = tid; q < 8192; q += 256){        // stage fcW [64][512] -> f16 LDS (overlay WA/WB)
    int i = q >> 7, kq = q & 127;
    float4 v = *(const float4*)(fcW + (i<<9) + (kq<<2));
    f16* p = (f16*)(lds + L_WA + (i<<10) + (kq<<3));
    p[0]=(f16)v.x; p[1]=(f16)v.y; p[2]=(f16)v.z; p[3]=(f16)v.w;
  }
  __syncthreads();
  {
    int tl = tid >> 7;
    int t  = (cg<<1) + tl;                      // 64 col-groups x 2 = all 128 timesteps
    int r  = (tid>>2) & 31;
    int iq = tid & 3;
    const char* hsrow = HS + (((t<<7) + b0 + r)<<10);
    float acc[16];
#pragma unroll
    for (int ii = 0; ii < 16; ++ii) acc[ii] = 0.f;
    for (int k8 = 0; k8 < 64; ++k8){
      f16x8 hv = *(const f16x8*)(hsrow + (k8<<4));
#pragma unroll
      for (int ii = 0; ii < 16; ++ii){
        f16x8 wv = *(const f16x8*)(lds + L_WA + (((iq<<4)+ii)<<10) + (k8<<4));
#pragma unroll
        for (int j = 0; j < 8; ++j) acc[ii] += (float)hv[j] * (float)wv[j];
      }
    }
#pragma unroll
    for (int ii = 0; ii < 16; ++ii){
      int i = (iq<<4) + ii;
      out[((((b0+r)<<7) + t)<<6) + i] = acc[ii] + fcb[i];
    }
  }
}

extern "C" void kernel_launch(void* const* d_in, const int* in_sizes, int n_in,
                              void* d_out, int out_size, void* d_ws, size_t ws_size,
                              hipStream_t stream){
  const float* x     = (const float*)d_in[0];
  const float* eWih0 = (const float*)d_in[1];
  const float* eWhh0 = (const float*)d_in[2];
  const float* ebi0  = (const float*)d_in[3];
  const float* ebh0  = (const float*)d_in[4];
  const float* eWih1 = (const float*)d_in[5];
  const float* eWhh1 = (const float*)d_in[6];
  const float* ebi1  = (const float*)d_in[7];
  const float* ebh1  = (const float*)d_in[8];
  const float* dWih0 = (const float*)d_in[9];
  const float* dWhh0 = (const float*)d_in[10];
  const float* dbi0  = (const float*)d_in[11];
  const float* dbh0  = (const float*)d_in[12];
  const float* dWih1 = (const float*)d_in[13];
  const float* dWhh1 = (const float*)d_in[14];
  const float* dbi1  = (const float*)d_in[15];
  const float* dbh1  = (const float*)d_in[16];
  const float* fcW   = (const float*)d_in[17];
  const float* fcb   = (const float*)d_in[18];
  char* ws = (char*)d_ws;

  hipMemsetAsync(d_ws, 0, OFF_XH, stream);       // zero barrier flags + all h double-buffers
  cvt_x<<<512, 256, 0, stream>>>(x, ws);
  lstm_persist<<<256, 256, 0, stream>>>(eWih0,eWhh0,ebi0,ebh0,eWih1,eWhh1,ebi1,ebh1,
                                        dWih0,dWhh0,dbi0,dbh0,dWih1,dWhh1,dbi1,dbh1,
                                        fcW,fcb,(float*)d_out,ws);
}